// Round 3
// baseline (704.678 us; speedup 1.0000x reference)
//
#include <hip/hip_runtime.h>

#define BB 256
#define TT 2048
#define FF 64
#define HH 32
#define G4 128
#define K2E 1.4426950408889634f

typedef float f32x2 __attribute__((ext_vector_type(2)));

__device__ __forceinline__ float fast_rcp(float x){ return __builtin_amdgcn_rcpf(x); }
__device__ __forceinline__ float fast_exp2(float x){
#if __has_builtin(__builtin_amdgcn_exp2f)
  return __builtin_amdgcn_exp2f(x);
#else
  return exp2f(x);
#endif
}
// v_permlane32_swap: swaps one operand's half with the other's opposite half.
// With a==b==v on input, outputs are {bcast(v_lo), bcast(v_hi)} (order fixed by ISA).
__device__ __forceinline__ void swap_halves(float &a, float &b){
#if __has_builtin(__builtin_amdgcn_permlane32_swap)
  typedef int i32x2_ __attribute__((ext_vector_type(2)));
  i32x2_ r = __builtin_amdgcn_permlane32_swap(__float_as_int(a), __float_as_int(b), false, false);
  a = __int_as_float(r.x);
  b = __int_as_float(r.y);
#else
  asm("v_permlane32_swap_b32 %0, %1" : "+v"(a), "+v"(b));
#endif
}

// packed fp32 FMA
#define PKFMA_VV(acc, a, b) asm("v_pk_fma_f32 %0, %1, %2, %0" : "+v"(acc) : "v"(a), "v"(b))
#define PKFMA_SV(acc, a, b) asm("v_pk_fma_f32 %0, %1, %2, %0" : "+v"(acc) : "s"(a), "v"(b))

// ---------------- Phase 1: xg = (x @ Wx + b) * colscale ----------------
// colscale folds the exp->exp2 conversion and sigmoid/tanh argument scaling:
// cols 0-63 (i,f): -log2e ; 64-95 (g): +2*log2e ; 96-127 (o): -log2e.
__global__ __launch_bounds__(256) void lstm_gemm(const float* __restrict__ x,
    const float* __restrict__ Wx, const float* __restrict__ bias,
    float* __restrict__ xg, int t0, int ct)
{
  __shared__ float sW[FF*G4];
  __shared__ float sB[G4];
  __shared__ float sX[64*68];
  int tid = threadIdx.x;
  {
    const float4* Wx4 = (const float4*)Wx;
    float4* sW4 = (float4*)sW;
#pragma unroll
    for (int q=0;q<8;q++) sW4[q*256+tid] = Wx4[q*256+tid];
    if (tid < 32) ((float4*)sB)[tid] = ((const float4*)bias)[tid];
  }
  long total = (long)BB*ct;
  long m0 = (long)blockIdx.x * 64;
#pragma unroll
  for (int s=0;s<4;s++){
    int idx = tid + s*256;
    int row = idx >> 4, q = idx & 15;
    long gm = m0 + row;
    float4 v = make_float4(0.f,0.f,0.f,0.f);
    if (gm < total){
      int bidx = (int)((unsigned long)gm / (unsigned)ct);
      int tt   = (int)(gm - (long)bidx*ct);
      v = ((const float4*)(x + ((size_t)bidx*TT + t0 + tt)*FF))[q];
    }
    *(float4*)&sX[row*68 + q*4] = v;
  }
  __syncthreads();
  int rg = tid >> 5;
  int cg = tid & 31;
  int r0 = rg*8;
  f32x2 acc[8][4];
#pragma unroll
  for (int r=0;r<8;r++)
#pragma unroll
    for (int c=0;c<4;c++) acc[r][c] = (f32x2){0.f,0.f};
#pragma unroll 8
  for (int kp=0; kp<32; kp++){
    int k = kp*2;
    f32x2 xv[8];
#pragma unroll
    for (int r=0;r<8;r++) xv[r] = *(const f32x2*)&sX[(r0+r)*68 + k];
    f32x2 wv[4];
#pragma unroll
    for (int c=0;c<4;c++){
      f32x2 w; w.x = sW[k*G4 + cg + 32*c]; w.y = sW[(k+1)*G4 + cg + 32*c];
      wv[c] = w;
    }
#pragma unroll
    for (int r=0;r<8;r++)
#pragma unroll
      for (int c=0;c<4;c++) PKFMA_VV(acc[r][c], xv[r], wv[c]);
  }
  const float csc[4] = {-K2E, -K2E, 2.f*K2E, -K2E};
#pragma unroll
  for (int r=0;r<8;r++){
    long gm = m0 + r0 + r;
    if (gm < total){
      float* o = xg + (size_t)gm*G4;
#pragma unroll
      for (int c=0;c<4;c++)
        o[cg + 32*c] = (acc[r][c].x + acc[r][c].y + sB[cg + 32*c]) * csc[c];
    }
  }
}

// ---------------- Phase 2: sequential scan ----------------
// One wave per batch row; lane l: unit j=l&31, half=l>>5, gate cols base=j+half*64 and base+32.
// Gates arrive pre-scaled so activations are A*rcp(1+exp2(g))+B.
__global__ __launch_bounds__(64, 1) void lstm_scan(const float* __restrict__ xg,
    const float* __restrict__ Wh, float* __restrict__ ys,
    float* __restrict__ state, int t0, int ct)
{
  int r = blockIdx.x;
  int l = threadIdx.x;
  int j = l & 31;
  int half = l >> 5;
  int base = j + half*64;

  float ws0 = half ? (2.f*K2E) : (-K2E);   // col base: i (sig) or g (tanh)
  float ws1 = -K2E;                        // col base+32: f or o (both sig)
  f32x2 wp0[16], wp1[16];
#pragma unroll
  for (int kk=0;kk<16;kk++){
    f32x2 a, b_;
    a.x  = Wh[(2*kk)*G4 + base]*ws0;       a.y  = Wh[(2*kk+1)*G4 + base]*ws0;
    b_.x = Wh[(2*kk)*G4 + base+32]*ws1;    b_.y = Wh[(2*kk+1)*G4 + base+32]*ws1;
    wp0[kk]=a; wp1[kk]=b_;
  }
  // Pin Wh fragments in VGPRs: asm-defined values cannot be rematerialized as reloads.
#pragma unroll
  for (int kk=0;kk<16;kk++){ asm volatile("" : "+v"(wp0[kk]), "+v"(wp1[kk])); }

  float A0 = half ? -2.f : 1.f;
  float B0 = half ?  1.f : 0.f;

  float cc, hcur;
  if (t0 == 0){ cc = 0.f; hcur = 0.f; }
  else { cc = state[r*HH + j]; hcur = state[BB*HH + r*HH + j]; }

  const float* xp = xg + (size_t)r*ct*G4 + base;
  float* yp = ys + ((size_t)r*TT + t0)*HH;

  float px0[8], px1[8];
#pragma unroll
  for (int u=0;u<8;u++){
    int t_ = (u < ct) ? u : (ct-1);
    px0[u] = xp[(size_t)t_*G4];
    px1[u] = xp[(size_t)t_*G4 + 32];
  }

  float hprev = hcur;

  auto STEP = [&](float xv0, float xv1){
    // broadcast h (lanes 0..31) into SGPR pairs
    f32x2 hp[16];
#pragma unroll
    for (int kk=0;kk<16;kk++){
      f32x2 p;
      p.x = __int_as_float(__builtin_amdgcn_readlane(__float_as_int(hcur), 2*kk));
      p.y = __int_as_float(__builtin_amdgcn_readlane(__float_as_int(hcur), 2*kk+1));
      hp[kk] = p;
    }
    f32x2 aA, aB, bA, bB;
    aA.x = xv0; aA.y = 0.f; aB.x = 0.f; aB.y = 0.f;
    bA.x = xv1; bA.y = 0.f; bB.x = 0.f; bB.y = 0.f;
#pragma unroll
    for (int kk=0;kk<8;kk++){
      PKFMA_SV(aA, hp[2*kk],   wp0[2*kk]);
      PKFMA_SV(aB, hp[2*kk+1], wp0[2*kk+1]);
      PKFMA_SV(bA, hp[2*kk],   wp1[2*kk]);
      PKFMA_SV(bB, hp[2*kk+1], wp1[2*kk+1]);
    }
    float g1 = (bA.x+bB.x)+(bA.y+bB.y);
    float t1v = fast_rcp(1.f + fast_exp2(g1));     // lower: sig(f), upper: sig(o)
    float oth = __shfl_xor(t1v, 32);               // issued early; latency hides under t0v chain
    float g0 = (aA.x+aB.x)+(aA.y+aB.y);
    float t0v = fmaf(A0, fast_rcp(1.f + fast_exp2(g0)), B0);  // lower: sig(i), upper: tanh(g)
    float u_ = t0v, w_ = t0v;
    swap_halves(u_, w_);                           // {bcast lo, bcast hi} in either order
    float ig = u_ * w_;                            // sig(i)*tanh(g), all lanes, order-invariant
    float sf = half ? oth : t1v;
    float so = half ? t1v : oth;
    cc = fmaf(sf, cc, ig);
    float tc = fmaf(-2.f, fast_rcp(1.f + fast_exp2((2.f*K2E)*cc)), 1.f);
    hcur = so * tc;                                // valid in ALL lanes
  };

  int tb = 0;
  for (; tb + 8 <= ct; tb += 8){
#pragma unroll
    for (int u=0;u<8;u++){
      int t = tb + u;
      float xv0 = px0[u], xv1 = px1[u];
      int tn = t + 8; if (tn > ct-1) tn = ct-1;
      px0[u] = xp[(size_t)tn*G4];
      px1[u] = xp[(size_t)tn*G4 + 32];
      STEP(xv0, xv1);
      if (u & 1){
        // paired store: lanes 0-31 write h[t-1], lanes 32-63 write h[t] (contiguous 256B)
        float sv = half ? hcur : hprev;
        yp[(size_t)(t-1)*HH + l] = sv;
      } else {
        hprev = hcur;
      }
    }
  }
  for (int u=0; tb+u < ct; ++u){
    STEP(px0[u], px1[u]);
    if (half == 0) yp[(size_t)(tb+u)*HH + j] = hcur;
  }

  if (half == 0){
    state[r*HH + j] = cc;
    state[BB*HH + r*HH + j] = hcur;
  }
}

extern "C" void kernel_launch(void* const* d_in, const int* in_sizes, int n_in,
                              void* d_out, int out_size, void* d_ws, size_t ws_size,
                              hipStream_t stream)
{
  const float* x  = (const float*)d_in[0];
  const float* Wx = (const float*)d_in[1];
  const float* Wh = (const float*)d_in[2];
  const float* b  = (const float*)d_in[3];
  float* ys = (float*)d_out;
  char* ws = (char*)d_ws;
  float* state = (float*)ws;                 // c: BB*HH, h: BB*HH
  float* xg = (float*)(ws + 65536);
  size_t per_step = (size_t)BB * G4 * sizeof(float);
  size_t avail = ws_size > 65536 ? ws_size - 65536 : 0;
  long ctl = (long)(avail / per_step);
  int CT = (ctl >= TT) ? TT : (int)ctl;
  if (CT < 1) CT = 1;
  for (int t0 = 0; t0 < TT; t0 += CT){
    int ct = (TT - t0 < CT) ? (TT - t0) : CT;
    int wgs = (int)(((long)BB*ct + 63)/64);
    lstm_gemm<<<dim3(wgs), dim3(256), 0, stream>>>(x, Wx, b, xg, t0, ct);
    lstm_scan<<<dim3(256), dim3(64), 0, stream>>>(xg, Wh, ys, state, t0, ct);
  }
}

// Round 4
// 669.490 us; speedup vs baseline: 1.0526x; 1.0526x over previous
//
#include <hip/hip_runtime.h>

#define BB 256
#define TT 2048
#define FF 64
#define HH 32
#define G4 128
#define K2E 1.4426950408889634f

typedef float f32x2 __attribute__((ext_vector_type(2)));

__device__ __forceinline__ float fast_rcp(float x){ return __builtin_amdgcn_rcpf(x); }
__device__ __forceinline__ float fast_exp2(float x){
#if __has_builtin(__builtin_amdgcn_exp2f)
  return __builtin_amdgcn_exp2f(x);
#else
  return exp2f(x);
#endif
}
// v_permlane32_swap_b32: exchanges one half of a with the opposite half of b.
// With a==b==v on input: one output becomes bcast(lower-counterpart value), the
// other bcast(upper-counterpart value) — order fixed by HW, resolved at runtime
// via a loop-invariant probe (see dprobe below).
__device__ __forceinline__ void swap_halves(float &a, float &b){
#if __has_builtin(__builtin_amdgcn_permlane32_swap)
  typedef int i32x2_ __attribute__((ext_vector_type(2)));
  i32x2_ r = __builtin_amdgcn_permlane32_swap(__float_as_int(a), __float_as_int(b), false, false);
  a = __int_as_float(r.x);
  b = __int_as_float(r.y);
#else
  asm("v_permlane32_swap_b32 %0, %1" : "+v"(a), "+v"(b));
#endif
}

#define PKFMA_VV(acc, a, b) asm("v_pk_fma_f32 %0, %1, %2, %0" : "+v"(acc) : "v"(a), "v"(b))
#define PKFMA_SV(acc, a, b) asm("v_pk_fma_f32 %0, %1, %2, %0" : "+v"(acc) : "s"(a), "v"(b))

// ---------------- Phase 1: xg = (x @ Wx + b) * colscale ----------------
// colscale folds exp->exp2 and the sigmoid/tanh argument scaling:
// cols 0-63 (i,f): -log2e ; 64-95 (g): +2*log2e ; 96-127 (o): -log2e.
__global__ __launch_bounds__(256) void lstm_gemm(const float* __restrict__ x,
    const float* __restrict__ Wx, const float* __restrict__ bias,
    float* __restrict__ xg, int t0, int ct)
{
  __shared__ float sW[FF*G4];
  __shared__ float sB[G4];
  __shared__ float sX[64*68];
  int tid = threadIdx.x;
  {
    const float4* Wx4 = (const float4*)Wx;
    float4* sW4 = (float4*)sW;
#pragma unroll
    for (int q=0;q<8;q++) sW4[q*256+tid] = Wx4[q*256+tid];
    if (tid < 32) ((float4*)sB)[tid] = ((const float4*)bias)[tid];
  }
  long total = (long)BB*ct;
  long m0 = (long)blockIdx.x * 64;
#pragma unroll
  for (int s=0;s<4;s++){
    int idx = tid + s*256;
    int row = idx >> 4, q = idx & 15;
    long gm = m0 + row;
    float4 v = make_float4(0.f,0.f,0.f,0.f);
    if (gm < total){
      int bidx = (int)((unsigned long)gm / (unsigned)ct);
      int tt   = (int)(gm - (long)bidx*ct);
      v = ((const float4*)(x + ((size_t)bidx*TT + t0 + tt)*FF))[q];
    }
    *(float4*)&sX[row*68 + q*4] = v;
  }
  __syncthreads();
  int rg = tid >> 5;
  int cg = tid & 31;
  int r0 = rg*8;
  f32x2 acc[8][4];
#pragma unroll
  for (int r=0;r<8;r++)
#pragma unroll
    for (int c=0;c<4;c++) acc[r][c] = (f32x2){0.f,0.f};
#pragma unroll 8
  for (int kp=0; kp<32; kp++){
    int k = kp*2;
    f32x2 xv[8];
#pragma unroll
    for (int r=0;r<8;r++) xv[r] = *(const f32x2*)&sX[(r0+r)*68 + k];
    f32x2 wv[4];
#pragma unroll
    for (int c=0;c<4;c++){
      f32x2 w; w.x = sW[k*G4 + cg + 32*c]; w.y = sW[(k+1)*G4 + cg + 32*c];
      wv[c] = w;
    }
#pragma unroll
    for (int r=0;r<8;r++)
#pragma unroll
      for (int c=0;c<4;c++) PKFMA_VV(acc[r][c], xv[r], wv[c]);
  }
  const float csc[4] = {-K2E, -K2E, 2.f*K2E, -K2E};
#pragma unroll
  for (int r=0;r<8;r++){
    long gm = m0 + r0 + r;
    if (gm < total){
      float* o = xg + (size_t)gm*G4;
#pragma unroll
      for (int c=0;c<4;c++)
        o[cg + 32*c] = (acc[r][c].x + acc[r][c].y + sB[cg + 32*c]) * csc[c];
    }
  }
}

// ---------------- Phase 2: sequential scan ----------------
// One wave per batch row; lane l: unit j=l&31, half=l>>5, gate cols base=j+half*64, base+32.
// Gates arrive pre-scaled so activations are A*rcp(1+exp2(g))+B.
__global__ __launch_bounds__(64)
__attribute__((amdgpu_waves_per_eu(1,1)))   // pin occupancy target: allocator may use full VGPR budget, no spill
void lstm_scan(const float* __restrict__ xg,
    const float* __restrict__ Wh, float* __restrict__ ys,
    float* __restrict__ state, int t0, int ct)
{
  int r = blockIdx.x;
  int l = threadIdx.x;
  int j = l & 31;
  int half = l >> 5;
  int base = j + half*64;

  float ws0 = half ? (2.f*K2E) : (-K2E);   // col base: i (sig) or g (tanh)
  float ws1 = -K2E;                        // col base+32: f or o (both sig)
  f32x2 wp0[16], wp1[16];
#pragma unroll
  for (int kk=0;kk<16;kk++){
    f32x2 a, b_;
    a.x  = Wh[(2*kk)*G4 + base]*ws0;       a.y  = Wh[(2*kk+1)*G4 + base]*ws0;
    b_.x = Wh[(2*kk)*G4 + base+32]*ws1;    b_.y = Wh[(2*kk+1)*G4 + base+32]*ws1;
    wp0[kk]=a; wp1[kk]=b_;
  }
#pragma unroll
  for (int kk=0;kk<16;kk++){ asm volatile("" : "+v"(wp0[kk]), "+v"(wp1[kk])); }

  float A0 = half ? -2.f : 1.f;
  float B0 = half ?  1.f : 0.f;

  // Direction probe for permlane32_swap (loop-invariant): da ends up holding,
  // uniformly in every lane, the value that came from the UPPER or LOWER half
  // depending on the HW's output order. flip==true  ->  first output holds the
  // upper-half (o-gate) value.
  float da = (float)half, db = (float)half;
  swap_halves(da, db);
  bool flip = (da != 0.0f);

  float cc, hcur;
  if (t0 == 0){ cc = 0.f; hcur = 0.f; }
  else { cc = state[r*HH + j]; hcur = state[BB*HH + r*HH + j]; }

  const float* xp = xg + (size_t)r*ct*G4 + base;
  float* yp = ys + ((size_t)r*TT + t0)*HH;

  float px0[8], px1[8];
#pragma unroll
  for (int u=0;u<8;u++){
    int t_ = (u < ct) ? u : (ct-1);
    px0[u] = xp[(size_t)t_*G4];
    px1[u] = xp[(size_t)t_*G4 + 32];
  }

  auto STEP = [&](float xv0, float xv1){
    // broadcast h (identical in both halves) into SGPR pairs
    f32x2 hp[16];
#pragma unroll
    for (int kk=0;kk<16;kk++){
      f32x2 p;
      p.x = __int_as_float(__builtin_amdgcn_readlane(__float_as_int(hcur), 2*kk));
      p.y = __int_as_float(__builtin_amdgcn_readlane(__float_as_int(hcur), 2*kk+1));
      hp[kk] = p;
    }
    // 8 independent accumulator chains, depth 4
    f32x2 q0,q1,q2,q3,s0,s1,s2,s3;
    q0.x = xv0; q0.y = 0.f; q1 = (f32x2){0.f,0.f}; q2 = (f32x2){0.f,0.f}; q3 = (f32x2){0.f,0.f};
    s0.x = xv1; s0.y = 0.f; s1 = (f32x2){0.f,0.f}; s2 = (f32x2){0.f,0.f}; s3 = (f32x2){0.f,0.f};
#pragma unroll
    for (int kk=0;kk<4;kk++){
      PKFMA_SV(q0, hp[4*kk+0], wp0[4*kk+0]);
      PKFMA_SV(q1, hp[4*kk+1], wp0[4*kk+1]);
      PKFMA_SV(q2, hp[4*kk+2], wp0[4*kk+2]);
      PKFMA_SV(q3, hp[4*kk+3], wp0[4*kk+3]);
      PKFMA_SV(s0, hp[4*kk+0], wp1[4*kk+0]);
      PKFMA_SV(s1, hp[4*kk+1], wp1[4*kk+1]);
      PKFMA_SV(s2, hp[4*kk+2], wp1[4*kk+2]);
      PKFMA_SV(s3, hp[4*kk+3], wp1[4*kk+3]);
    }
    f32x2 qs = (q0+q1)+(q2+q3);
    f32x2 ss = (s0+s1)+(s2+s3);
    float g0 = qs.x + qs.y;
    float g1 = ss.x + ss.y;
    float t1v = fast_rcp(1.f + fast_exp2(g1));                // lower: sig(f), upper: sig(o)
    float t0v = fmaf(A0, fast_rcp(1.f + fast_exp2(g0)), B0);  // lower: sig(i), upper: tanh(g)
    // i*g product: order-invariant
    float si = t0v, tg = t0v;
    swap_halves(si, tg);
    float ig = si * tg;
    // f/o exchange: direction-proof via probe
    float e0 = t1v, e1 = t1v;
    swap_halves(e0, e1);
    float sf = flip ? e1 : e0;
    float so = flip ? e0 : e1;
    cc = fmaf(sf, cc, ig);
    float tc = fmaf(-2.f, fast_rcp(1.f + fast_exp2((2.f*K2E)*cc)), 1.f);
    hcur = so * tc;                                           // valid in ALL lanes
  };

  int tb = 0;
  for (; tb + 8 <= ct; tb += 8){
#pragma unroll
    for (int u=0;u<8;u++){
      int t = tb + u;
      float xv0 = px0[u], xv1 = px1[u];
      int tn = t + 8; if (tn > ct-1) tn = ct-1;
      px0[u] = xp[(size_t)tn*G4];
      px1[u] = xp[(size_t)tn*G4 + 32];
      STEP(xv0, xv1);
      if (half == 0) yp[(size_t)t*HH + j] = hcur;   // 128B store, off the carry chain
    }
  }
  for (int u=0; tb+u < ct; ++u){
    STEP(px0[u], px1[u]);
    if (half == 0) yp[(size_t)(tb+u)*HH + j] = hcur;
  }

  if (half == 0){
    state[r*HH + j] = cc;
    state[BB*HH + r*HH + j] = hcur;
  }
}

extern "C" void kernel_launch(void* const* d_in, const int* in_sizes, int n_in,
                              void* d_out, int out_size, void* d_ws, size_t ws_size,
                              hipStream_t stream)
{
  const float* x  = (const float*)d_in[0];
  const float* Wx = (const float*)d_in[1];
  const float* Wh = (const float*)d_in[2];
  const float* b  = (const float*)d_in[3];
  float* ys = (float*)d_out;
  char* ws = (char*)d_ws;
  float* state = (float*)ws;                 // c: BB*HH, h: BB*HH
  float* xg = (float*)(ws + 65536);
  size_t per_step = (size_t)BB * G4 * sizeof(float);
  size_t avail = ws_size > 65536 ? ws_size - 65536 : 0;
  long ctl = (long)(avail / per_step);
  int CT = (ctl >= TT) ? TT : (int)ctl;
  if (CT < 1) CT = 1;
  for (int t0 = 0; t0 < TT; t0 += CT){
    int ct = (TT - t0 < CT) ? (TT - t0) : CT;
    int wgs = (int)(((long)BB*ct + 63)/64);
    lstm_gemm<<<dim3(wgs), dim3(256), 0, stream>>>(x, Wx, b, xg, t0, ct);
    lstm_scan<<<dim3(256), dim3(64), 0, stream>>>(xg, Wh, ys, state, t0, ct);
  }
}